// Round 7
// baseline (49.582 us; speedup 1.0000x reference)
//
#include <hip/hip_runtime.h>

#define NB 128
#define NC 16
#define NT 16384
#define NW 4096

__global__ __launch_bounds__(256) void rww_kernel(
    const float* __restrict__ x,
    const int* __restrict__ window_starts,
    const int* __restrict__ new_len,
    float* __restrict__ out)
{
    const int b = blockIdx.y;
    const int t = blockIdx.x * 256 + threadIdx.x;

    const int s  = window_starts[b];
    const int nl = new_len[b];
    const float sf  = (float)s;
    const float nlf = (float)nl;
    const int   L   = NT + nl - NW;
    const float Lf  = (float)L;

    // Stage 2 query position: q = t*(L-1)/(T-1)
    float qpos = (float)t * (Lf - 1.0f) / (float)(NT - 1);
    int   qlo  = (int)floorf(qpos);
    int   qhi  = min(qlo + 1, L - 1);
    float qf   = qpos - (float)qlo;
    const float gq = 1.0f - qf;

    const float* xb = x   + (size_t)b * NC * NT;
    float*       ob = out + (size_t)b * NC * NT;

    // Fast path: both stage-2 taps strictly outside the warp window -> the
    // stage-1 positions are exact integers (f=0), so each warped tap is one
    // source sample. Bit-identical to the general path (f=0/g=1 exact).
    bool before = (qhi < s);
    bool after  = ((float)qlo >= sf + nlf);
    if (before || after) {
        const int off = after ? (NW - nl) : 0;
        const int i0 = qlo + off;
        const int i1 = qhi + off;
        // Phase 1: issue ALL loads (32 in flight, one wait) ----------------
        float a[NC], c2[NC];
        #pragma unroll
        for (int c = 0; c < NC; ++c) {
            const float* xc = xb + c * NT;
            a[c]  = xc[i0];
            c2[c] = xc[i1];
        }
        // Phase 2: compute + store -----------------------------------------
        #pragma unroll
        for (int c = 0; c < NC; ++c) {
            __builtin_nontemporal_store(a[c] * gq + c2[c] * qf, ob + c * NT + t);
        }
        return;
    }

    // General path (window / straddle): 4-tap
    const float den = fmaxf(nlf - 1.0f, 1.0f);
    int lo0, hi0, lo1, hi1;
    float f0, f1;
    {
        float jf = (float)qlo;
        float pos;
        if (jf >= sf + nlf)      pos = jf - nlf + (float)NW;
        else if (jf >= sf)       pos = sf + (jf - sf) * (float)(NW - 1) / den;
        else                     pos = jf;
        pos = fminf(fmaxf(pos, 0.0f), (float)(NT - 1));
        lo0 = (int)floorf(pos);
        hi0 = min(lo0 + 1, NT - 1);
        f0  = pos - (float)lo0;
    }
    {
        float jf = (float)qhi;
        float pos;
        if (jf >= sf + nlf)      pos = jf - nlf + (float)NW;
        else if (jf >= sf)       pos = sf + (jf - sf) * (float)(NW - 1) / den;
        else                     pos = jf;
        pos = fminf(fmaxf(pos, 0.0f), (float)(NT - 1));
        lo1 = (int)floorf(pos);
        hi1 = min(lo1 + 1, NT - 1);
        f1  = pos - (float)lo1;
    }

    const float g0 = 1.0f - f0;
    const float g1 = 1.0f - f1;

    // Phase 1: all 64 taps in flight ---------------------------------------
    float A0[NC], B0[NC], A1[NC], B1[NC];
    #pragma unroll
    for (int c = 0; c < NC; ++c) {
        const float* xc = xb + c * NT;
        A0[c] = xc[lo0];
        B0[c] = xc[hi0];
        A1[c] = xc[lo1];
        B1[c] = xc[hi1];
    }
    // Phase 2: compute + store ---------------------------------------------
    #pragma unroll
    for (int c = 0; c < NC; ++c) {
        float v0 = A0[c] * g0 + B0[c] * f0;   // warped[qlo]
        float v1 = A1[c] * g1 + B1[c] * f1;   // warped[qhi]
        __builtin_nontemporal_store(v0 * gq + v1 * qf, ob + c * NT + t);
    }
}

extern "C" void kernel_launch(void* const* d_in, const int* in_sizes, int n_in,
                              void* d_out, int out_size, void* d_ws, size_t ws_size,
                              hipStream_t stream) {
    const float* x   = (const float*)d_in[0];
    const int*   ws  = (const int*)d_in[1];
    const int*   nl  = (const int*)d_in[2];
    float*       out = (float*)d_out;

    dim3 grid(NT / 256, NB);
    dim3 block(256);
    rww_kernel<<<grid, block, 0, stream>>>(x, ws, nl, out);
}

// Round 8
// 47.285 us; speedup vs baseline: 1.0486x; 1.0486x over previous
//
#include <hip/hip_runtime.h>

#define NB 128
#define NC 16
#define NT 16384
#define NW 4096
#define TPB 256
#define SPANROW 512          // LDS row capacity (floats); max true span ~452

typedef float f32x4 __attribute__((ext_vector_type(4)));

// One block = (sample b, 256 consecutive outputs t0..t0+255), all 16 channels.
// Stage exactly the needed source span (positions are monotone in t) with
// coalesced float4 loads; compute from LDS; store float4 (4 t's per thread).
__global__ __launch_bounds__(256) void rww_kernel(
    const float* __restrict__ x,
    const int* __restrict__ window_starts,
    const int* __restrict__ new_len,
    float* __restrict__ out)
{
    __shared__ float lds[NC][SPANROW];

    const int b   = blockIdx.y;
    const int t0  = blockIdx.x * TPB;
    const int tid = threadIdx.x;

    const int s  = window_starts[b];
    const int nl = new_len[b];
    const float sf  = (float)s;
    const float nlf = (float)nl;
    const float den = fmaxf(nlf - 1.0f, 1.0f);
    const int   L   = NT + nl - NW;
    const float Lf  = (float)L;

    // exact stage-1 position for a warped index j (same float ops as before)
    auto pos_of = [&](int j) -> float {
        float jf = (float)j;
        float pos;
        if (jf >= sf + nlf)      pos = jf - nlf + (float)NW;
        else if (jf >= sf)       pos = sf + (jf - sf) * (float)(NW - 1) / den;
        else                     pos = jf;
        return fminf(fmaxf(pos, 0.0f), (float)(NT - 1));
    };

    // ---- block-exact source window [winstart, winstart+span) ----
    int winstart, span;
    {
        float qp0 = (float)t0 * (Lf - 1.0f) / (float)(NT - 1);
        int   jlo = (int)floorf(qp0);
        float qpm = (float)(t0 + TPB - 1) * (Lf - 1.0f) / (float)(NT - 1);
        int   jhi = min((int)floorf(qpm) + 1, L - 1);
        float pmin = pos_of(jlo);
        float pmax = pos_of(jhi);
        winstart = ((int)floorf(pmin)) & ~3;
        if (winstart < 0) winstart = 0;
        int need_end = min((int)floorf(pmax) + 2, NT);   // +1 hi tap, +1 excl
        span = (need_end - winstart + 3) & ~3;
        if (span > SPANROW) span = SPANROW;
        if (winstart + span > NT) winstart = NT - span;
    }

    // ---- stage: 16 rows x span floats, coalesced float4 ----
    const float* xb = x + (size_t)b * NC * NT;
    const int nv = span >> 2;                 // float4 slots per row (<=128)
    #pragma unroll
    for (int it = 0; it < 8; ++it) {          // 16 rows x 128 slots / 256 thr
        int idx  = it * TPB + tid;
        int c    = idx >> 7;                  // row
        int col4 = idx & 127;                 // float4 slot in row
        if (col4 < nv) {
            f32x4 v = *(const f32x4*)(xb + c * NT + winstart + col4 * 4);
            *(f32x4*)&lds[c][col4 * 4] = v;
        }
    }
    __syncthreads();

    // ---- per-thread: 4 consecutive t's (tq), 4 channels (c0..c0+3) ----
    const int tq = tid & 63;
    const int c0 = (tid >> 6) * 4;

    float g0a[4], f0a[4], g1a[4], f1a[4], gqa[4], qfa[4];
    int   r0l[4], r0h[4], r1l[4], r1h[4];
    #pragma unroll
    for (int i = 0; i < 4; ++i) {
        const int t = t0 + tq * 4 + i;
        float qpos = (float)t * (Lf - 1.0f) / (float)(NT - 1);
        int   qlo  = (int)floorf(qpos);
        int   qhi  = min(qlo + 1, L - 1);
        float qf   = qpos - (float)qlo;

        float p0 = pos_of(qlo);
        int lo0 = (int)floorf(p0);
        int hi0 = min(lo0 + 1, NT - 1);
        f0a[i] = p0 - (float)lo0;
        g0a[i] = 1.0f - f0a[i];
        r0l[i] = lo0 - winstart;
        r0h[i] = hi0 - winstart;

        float p1 = pos_of(qhi);
        int lo1 = (int)floorf(p1);
        int hi1 = min(lo1 + 1, NT - 1);
        f1a[i] = p1 - (float)lo1;
        g1a[i] = 1.0f - f1a[i];
        r1l[i] = lo1 - winstart;
        r1h[i] = hi1 - winstart;

        qfa[i] = qf;
        gqa[i] = 1.0f - qf;
    }

    float* ob = out + (size_t)b * NC * NT + t0 + tq * 4;
    #pragma unroll
    for (int cc = 0; cc < 4; ++cc) {
        const int c = c0 + cc;
        f32x4 r;
        #pragma unroll
        for (int i = 0; i < 4; ++i) {
            float a0 = lds[c][r0l[i]];
            float b0 = lds[c][r0h[i]];
            float a1 = lds[c][r1l[i]];
            float b1 = lds[c][r1h[i]];
            float v0 = a0 * g0a[i] + b0 * f0a[i];   // warped[qlo]
            float v1 = a1 * g1a[i] + b1 * f1a[i];   // warped[qhi]
            r[i] = v0 * gqa[i] + v1 * qfa[i];
        }
        __builtin_nontemporal_store(r, (f32x4*)(ob + c * NT));
    }
}

extern "C" void kernel_launch(void* const* d_in, const int* in_sizes, int n_in,
                              void* d_out, int out_size, void* d_ws, size_t ws_size,
                              hipStream_t stream) {
    const float* x   = (const float*)d_in[0];
    const int*   ws  = (const int*)d_in[1];
    const int*   nl  = (const int*)d_in[2];
    float*       out = (float*)d_out;

    dim3 grid(NT / TPB, NB);
    dim3 block(TPB);
    rww_kernel<<<grid, block, 0, stream>>>(x, ws, nl, out);
}

// Round 9
// 43.615 us; speedup vs baseline: 1.1368x; 1.0841x over previous
//
#include <hip/hip_runtime.h>

#define NB 128
#define NC 16
#define NT 16384
#define NW 4096
#define TPB 256
#define SPANROW 512          // LDS row capacity (floats); max true span ~455

typedef float f32x4 __attribute__((ext_vector_type(4)));

// One block = (sample b, 256 consecutive outputs), all 16 channels.
// XCD-swizzled 1D grid: all 64 t-blocks of a sample land on one XCD.
__global__ __launch_bounds__(256) void rww_kernel(
    const float* __restrict__ x,
    const int* __restrict__ window_starts,
    const int* __restrict__ new_len,
    float* __restrict__ out)
{
    __shared__ float lds[NC][SPANROW];

    // decode XCD-swizzled block id: i = ((b>>3)*64 + tc)*8 + (b&7)
    const int i_  = blockIdx.x;
    const int xcd = i_ & 7;
    const int j_  = i_ >> 3;
    const int tc  = j_ & 63;
    const int b   = ((j_ >> 6) << 3) + xcd;

    const int t0  = tc * TPB;
    const int tid = threadIdx.x;

    const int s  = window_starts[b];
    const int nl = new_len[b];
    const float sf  = (float)s;
    const float nlf = (float)nl;
    const float den = fmaxf(nlf - 1.0f, 1.0f);
    const int   L   = NT + nl - NW;
    const float Lf  = (float)L;

    auto pos_of = [&](int j) -> float {
        float jf = (float)j;
        float pos;
        if (jf >= sf + nlf)      pos = jf - nlf + (float)NW;
        else if (jf >= sf)       pos = sf + (jf - sf) * (float)(NW - 1) / den;
        else                     pos = jf;
        return fminf(fmaxf(pos, 0.0f), (float)(NT - 1));
    };

    // ---- block-exact source window [winstart, winstart+span) ----
    int winstart, span;
    {
        float qp0 = (float)t0 * (Lf - 1.0f) / (float)(NT - 1);
        int   jlo = (int)floorf(qp0);
        float qpm = (float)(t0 + TPB - 1) * (Lf - 1.0f) / (float)(NT - 1);
        int   jhi = min((int)floorf(qpm) + 1, L - 1);
        float pmin = pos_of(jlo);
        float pmax = pos_of(jhi);
        winstart = ((int)floorf(pmin)) & ~3;
        if (winstart < 0) winstart = 0;
        int need_end = min((int)floorf(pmax) + 2, NT);
        span = (need_end - winstart + 3) & ~3;
        if (span > SPANROW) span = SPANROW;
        if (winstart + span > NT) winstart = NT - span;
    }

    // ---- stage: 16 rows x span floats, coalesced float4 ----
    const float* xb = x + (size_t)b * NC * NT;
    const int nv = span >> 2;
    #pragma unroll
    for (int it = 0; it < 8; ++it) {
        int idx  = it * TPB + tid;
        int c    = idx >> 7;
        int col4 = idx & 127;
        if (col4 < nv) {
            f32x4 v = *(const f32x4*)(xb + c * NT + winstart + col4 * 4);
            *(f32x4*)&lds[c][col4 * 4] = v;
        }
    }
    __syncthreads();

    // ---- per-thread: 4 consecutive t's, 4 channels ----
    const int tq = tid & 63;
    const int c0 = (tid >> 6) * 4;

    bool  two[4];
    float f0a[4], g0a[4], f1a[4], g1a[4], gqa[4], qfa[4];
    int   r0l[4], r0h[4], r1l[4], r1h[4];
    #pragma unroll
    for (int i = 0; i < 4; ++i) {
        const int t = t0 + tq * 4 + i;
        float qpos = (float)t * (Lf - 1.0f) / (float)(NT - 1);
        int   qlo  = (int)floorf(qpos);
        int   qhi  = min(qlo + 1, L - 1);
        qfa[i] = qpos - (float)qlo;
        gqa[i] = 1.0f - qfa[i];

        bool before = (qhi < s);
        bool after  = ((float)qlo >= sf + nlf);
        two[i] = before || after;
        if (two[i]) {
            // outside window: stage-1 position exact integer (f=0)
            const int off = after ? (NW - nl) : 0;
            r0l[i] = qlo + off - winstart;
            r1l[i] = qhi + off - winstart;
            r0h[i] = r0l[i]; r1h[i] = r1l[i];
            f0a[i] = 0.0f; g0a[i] = 1.0f;
            f1a[i] = 0.0f; g1a[i] = 1.0f;
        } else {
            float p0 = pos_of(qlo);
            int lo0 = (int)floorf(p0);
            int hi0 = min(lo0 + 1, NT - 1);
            f0a[i] = p0 - (float)lo0;
            g0a[i] = 1.0f - f0a[i];
            r0l[i] = lo0 - winstart;
            r0h[i] = hi0 - winstart;

            float p1 = pos_of(qhi);
            int lo1 = (int)floorf(p1);
            int hi1 = min(lo1 + 1, NT - 1);
            f1a[i] = p1 - (float)lo1;
            g1a[i] = 1.0f - f1a[i];
            r1l[i] = lo1 - winstart;
            r1h[i] = hi1 - winstart;
        }
    }

    float* ob = out + (size_t)b * NC * NT + t0 + tq * 4;
    #pragma unroll
    for (int cc = 0; cc < 4; ++cc) {
        const int c = c0 + cc;
        f32x4 r;
        #pragma unroll
        for (int i = 0; i < 4; ++i) {
            if (two[i]) {
                // 2-tap exact path: halves LDS reads, conflict-free strides
                float a = lds[c][r0l[i]];
                float d = lds[c][r1l[i]];
                r[i] = a * gqa[i] + d * qfa[i];
            } else {
                float a0 = lds[c][r0l[i]];
                float b0 = lds[c][r0h[i]];
                float a1 = lds[c][r1l[i]];
                float b1 = lds[c][r1h[i]];
                float v0 = a0 * g0a[i] + b0 * f0a[i];
                float v1 = a1 * g1a[i] + b1 * f1a[i];
                r[i] = v0 * gqa[i] + v1 * qfa[i];
            }
        }
        __builtin_nontemporal_store(r, (f32x4*)(ob + c * NT));
    }
}

extern "C" void kernel_launch(void* const* d_in, const int* in_sizes, int n_in,
                              void* d_out, int out_size, void* d_ws, size_t ws_size,
                              hipStream_t stream) {
    const float* x   = (const float*)d_in[0];
    const int*   ws  = (const int*)d_in[1];
    const int*   nl  = (const int*)d_in[2];
    float*       out = (float*)d_out;

    dim3 grid(NT / TPB * NB);   // 8192 blocks, XCD-swizzled 1D
    dim3 block(TPB);
    rww_kernel<<<grid, block, 0, stream>>>(x, ws, nl, out);
}